// Round 1
// 4186.143 us; speedup vs baseline: 1.0712x; 1.0712x over previous
//
#include <hip/hip_runtime.h>
#include <hip/hip_bf16.h>
#include <stdint.h>

#define BB   64
#define TT   2048
#define II   256
#define HH   256
#define G4   1024   // 4*H
#define NC   10

typedef _Float16 half2v __attribute__((ext_vector_type(2)));
typedef _Float16 half8v __attribute__((ext_vector_type(8)));
typedef float    float4v __attribute__((ext_vector_type(4)));

__device__ __forceinline__ float fdot2(uint32_t w, uint32_t h, float acc) {
  return __builtin_amdgcn_fdot2(__builtin_bit_cast(half2v, w),
                                __builtin_bit_cast(half2v, h), acc, false);
}
__device__ __forceinline__ float sigmf(float v) { return 1.f / (1.f + __expf(-v)); }
__device__ __forceinline__ float tanhf2(float v) { float e = __expf(2.f * v); return 1.f - 2.f / (e + 1.f); }

// Barrier WITHOUT vmcnt drain: keeps the global xpk prefetch in flight.
__device__ __forceinline__ void bar_lds() {
  asm volatile("s_waitcnt lgkmcnt(0)\n\ts_barrier" ::: "memory");
}

// ---------------------------------------------------------------------------
// K0a: WcT[g][i] = sum_j key[i][j] * W_ih[g][j]  (f16), biasc[g] = b_ih+b_hh
// ---------------------------------------------------------------------------
__global__ __launch_bounds__(1024) void prep_wc(
    const float* __restrict__ key, const float* __restrict__ Wih,
    const float* __restrict__ bih, const float* __restrict__ bhh,
    _Float16* __restrict__ WcT, float* __restrict__ biasc) {
  __shared__ float krow[II];
  const int i = blockIdx.x;
  const int g = threadIdx.x;
  if (g < II) krow[g] = key[(size_t)i * II + g];
  __syncthreads();
  const float4* w4 = (const float4*)(Wih + (size_t)g * II);
  float acc = 0.f;
#pragma unroll 8
  for (int j = 0; j < II / 4; ++j) {
    float4 w = w4[j];
    acc += w.x * krow[4 * j] + w.y * krow[4 * j + 1] + w.z * krow[4 * j + 2] + w.w * krow[4 * j + 3];
  }
  WcT[(size_t)g * II + i] = (_Float16)acc;
  if (i == 0) biasc[g] = bih[g] + bhh[g];
}

// ---------------------------------------------------------------------------
// K0c: pack W_hh f16-pair dwords.
//   kp 0..111  -> wrg[kp][g]                (register-resident in lstm_seq)
//   kp 112..127-> wld[(c*512+t)*4+j] 16B blk (LDS-resident in lstm_seq)
//     where t = g&511, c = (g>>9)*4 + (kp-112)/4, j = (kp-112)&3
// ---------------------------------------------------------------------------
__global__ __launch_bounds__(256) void prep_whh(
    const float* __restrict__ Whh, uint32_t* __restrict__ wrg, uint32_t* __restrict__ wld) {
  const int id = blockIdx.x * 256 + threadIdx.x;   // 131072 = 1024 rows * 128 kp
  const int g  = id & (G4 - 1);
  const int kp = id >> 10;                          // 0..127
  float a = Whh[(size_t)g * HH + 2 * kp];
  float b = Whh[(size_t)g * HH + 2 * kp + 1];
  half2v h = {(_Float16)a, (_Float16)b};
  uint32_t packed = __builtin_bit_cast(uint32_t, h);
  if (kp < 112) {
    wrg[kp * G4 + g] = packed;
  } else {
    const int t = g & 511, hh = g >> 9;
    const int d = kp - 112;                         // 0..15
    const int c = hh * 4 + (d >> 2), j = d & 3;
    wld[(size_t)(c * 512 + t) * 4 + j] = packed;
  }
}

// ---------------------------------------------------------------------------
// K1: packed x-projection GEMM (unchanged). Logical x_proj[m][g]; stored as
//   [m][512] dwords: dword d = (x_proj[m][d], x_proj[m][d+512]) as f16 pair.
// ---------------------------------------------------------------------------
__global__ __launch_bounds__(256) void gemm_xproj(
    const float* __restrict__ x, const _Float16* __restrict__ WcT,
    const float* __restrict__ biasc, _Float16* __restrict__ xpk) {
  __shared__ __align__(16) _Float16 Asm[128][40];
  __shared__ __align__(16) _Float16 Bsm[128][40];
  const int t = threadIdx.x;
  const int n0 = blockIdx.x * 128;
  const int m0 = blockIdx.y * 128;
  const int r = t >> 1;
  const int hoff = (t & 1) * 16;
  const int lane = t & 63, wave = t >> 6;
  const int quad = lane >> 4, l15 = lane & 15;
  const int mh = (wave & 1) * 64, nh = (wave >> 1) * 64;
  float4v zero = {0.f, 0.f, 0.f, 0.f};
  float4v acc[4][4];
#pragma unroll
  for (int a = 0; a < 4; ++a)
#pragma unroll
    for (int b = 0; b < 4; ++b) acc[a][b] = zero;

  for (int kt = 0; kt < 8; ++kt) {
    const int k0 = kt * 32;
    const float4* xa = (const float4*)(x + (size_t)(m0 + r) * II + k0 + hoff);
    float4 f0 = xa[0], f1 = xa[1], f2 = xa[2], f3 = xa[3];
    half8v lo = {(_Float16)f0.x, (_Float16)f0.y, (_Float16)f0.z, (_Float16)f0.w,
                 (_Float16)f1.x, (_Float16)f1.y, (_Float16)f1.z, (_Float16)f1.w};
    half8v hi = {(_Float16)f2.x, (_Float16)f2.y, (_Float16)f2.z, (_Float16)f2.w,
                 (_Float16)f3.x, (_Float16)f3.y, (_Float16)f3.z, (_Float16)f3.w};
    const half8v* bsrc = (const half8v*)(WcT + (size_t)(n0 + r) * II + k0 + hoff);
    half8v b0 = bsrc[0], b1 = bsrc[1];
    *(half8v*)&Asm[r][hoff]     = lo;
    *(half8v*)&Asm[r][hoff + 8] = hi;
    *(half8v*)&Bsm[r][hoff]     = b0;
    *(half8v*)&Bsm[r][hoff + 8] = b1;
    __syncthreads();
    half8v af[4], bf[4];
#pragma unroll
    for (int mt = 0; mt < 4; ++mt) af[mt] = *(const half8v*)&Asm[mh + mt * 16 + l15][quad * 8];
#pragma unroll
    for (int nt = 0; nt < 4; ++nt) bf[nt] = *(const half8v*)&Bsm[nh + nt * 16 + l15][quad * 8];
#pragma unroll
    for (int mt = 0; mt < 4; ++mt)
#pragma unroll
      for (int nt = 0; nt < 4; ++nt)
        acc[mt][nt] = __builtin_amdgcn_mfma_f32_16x16x32_f16(af[mt], bf[nt], acc[mt][nt], 0, 0, 0);
    __syncthreads();
  }
  _Float16* dst = xpk;
#pragma unroll
  for (int nt = 0; nt < 4; ++nt) {
    const int col = n0 + nh + nt * 16 + l15;
    const float bias = biasc[col];
    const int cslot = (col & 511) * 2 + (col >> 9);
#pragma unroll
    for (int mt = 0; mt < 4; ++mt) {
      const int mrow = m0 + mh + mt * 16 + quad * 4;
#pragma unroll
      for (int j = 0; j < 4; ++j)
        dst[(size_t)(mrow + j) * 1024 + cslot] = (_Float16)(acc[mt][nt][j] + bias);
    }
  }
}

// ---------------------------------------------------------------------------
// K2: sequential LSTM. One WG / batch element; 512 threads; rows t0, t0+512.
// Weight split sized to the unified 256-reg/thread cap (2 waves/SIMD):
//   kpairs 0..111 of both rows -> 224 register dwords (fits with ~25 working)
//   kpairs 112..127            -> 64 KB LDS, ds_read_b128 per step
// h-broadcast rework (this round): h is wave-uniform, so instead of 32
// ds_read_b128 broadcast reads per thread (LDS-pipe bound: 320 b128
// wave-instrs/CU/step ~= 3.5k cyc), each wave does ONE ds_read_b64 (lane l
// gets h dwords 2l,2l+1), then v_readlane moves each of the 128 h dwords
// to an SGPR; v_dot2_f32_f16 consumes h straight from the SGPR operand.
// LDS instrs/CU/step: 320 -> ~80. Gate exchange: producers pre-activate
// f/o and write one float2 (ds_write_b64); consumer reads one ds_read_b64.
// ---------------------------------------------------------------------------
__global__ __launch_bounds__(512, 2) void lstm_seq(
    const uint32_t* __restrict__ xpk, const uint32_t* __restrict__ wrg,
    const uint4* __restrict__ wld, float* __restrict__ hfin) {
  __shared__ __align__(16) uint4 wsm[8 * 512];     // 64 KB weight tail
  __shared__ __align__(16) uint32_t hsm[128];      // 256 f16 h
  __shared__ __align__(16) float gsm[512];         // (f,o) activated pairs
  const int t0 = threadIdx.x, t1 = t0 + 512, b = blockIdx.x;
  const int lane = t0 & 63;

  uint32_t w0[112], w1[112];
#pragma unroll
  for (int c = 0; c < 112; ++c) { w0[c] = wrg[c * G4 + t0]; w1[c] = wrg[c * G4 + t1]; }
#pragma unroll
  for (int c = 0; c < 8; ++c) wsm[c * 512 + t0] = wld[c * 512 + t0];
  if (t0 < 128) hsm[t0] = 0;
  float cst = 0.f, hlast = 0.f;
  const uint32_t* xp = xpk + (size_t)b * TT * 512 + t0;
  uint32_t xn = xp[0];
  __syncthreads();

  for (int t = 0; t < TT; ++t) {
    const uint32_t xw = xn;
    xn = xp[(size_t)((t < TT - 1) ? t + 1 : t) * 512];   // prefetch next step
    // --- h distribute: 1 ds_read_b64/wave-lane; dword d lives in lane d>>1,
    //     reg d&1. readlane -> SGPR, fdot2 uses the SGPR as its h operand.
    uint2 hh2 = *(const uint2*)&hsm[2 * lane];
    uint32_t hv0 = hh2.x, hv1 = hh2.y;
    float a00 = 0.f, a01 = 0.f, a10 = 0.f, a11 = 0.f;
#pragma unroll
    for (int cc = 0; cc < 28; ++cc) {          // register-resident kpairs
      uint32_t hx = __builtin_amdgcn_readlane(hv0, 2 * cc);      // kpair 4cc+0
      uint32_t hy = __builtin_amdgcn_readlane(hv1, 2 * cc);      // kpair 4cc+1
      uint32_t hz = __builtin_amdgcn_readlane(hv0, 2 * cc + 1);  // kpair 4cc+2
      uint32_t hw = __builtin_amdgcn_readlane(hv1, 2 * cc + 1);  // kpair 4cc+3
      a00 = fdot2(w0[4 * cc + 0], hx, a00);
      a01 = fdot2(w0[4 * cc + 1], hy, a01);
      a00 = fdot2(w0[4 * cc + 2], hz, a00);
      a01 = fdot2(w0[4 * cc + 3], hw, a01);
      a10 = fdot2(w1[4 * cc + 0], hx, a10);
      a11 = fdot2(w1[4 * cc + 1], hy, a11);
      a10 = fdot2(w1[4 * cc + 2], hz, a10);
      a11 = fdot2(w1[4 * cc + 3], hw, a11);
    }
#pragma unroll
    for (int j = 0; j < 4; ++j) {              // LDS-resident tail kpairs 112+4j..
      uint32_t hx = __builtin_amdgcn_readlane(hv0, 56 + 2 * j);
      uint32_t hy = __builtin_amdgcn_readlane(hv1, 56 + 2 * j);
      uint32_t hz = __builtin_amdgcn_readlane(hv0, 57 + 2 * j);
      uint32_t hw = __builtin_amdgcn_readlane(hv1, 57 + 2 * j);
      uint4 wa = wsm[j * 512 + t0];
      uint4 wb = wsm[(4 + j) * 512 + t0];
      a00 = fdot2(wa.x, hx, a00);
      a01 = fdot2(wa.y, hy, a01);
      a00 = fdot2(wa.z, hz, a00);
      a01 = fdot2(wa.w, hw, a01);
      a10 = fdot2(wb.x, hx, a10);
      a11 = fdot2(wb.y, hy, a11);
      a10 = fdot2(wb.z, hz, a10);
      a11 = fdot2(wb.w, hw, a11);
    }
    half2v xh = __builtin_bit_cast(half2v, xw);
    const float s0 = (a00 + a01) + (float)xh.x;
    const float s1 = (a10 + a11) + (float)xh.y;
    float ig = 0.f, gg = 0.f;
    if (t0 < 256) {
      ig = sigmf(s0);                 // row t0       = i gate (pre-barrier)
      gg = tanhf2(s1);                // row t0+512   = g gate (pre-barrier)
    } else {
      float2 fo;                      // rows t0 (f), t0+512 (o): activate here
      fo.x = sigmf(s0);
      fo.y = sigmf(s1);
      *(float2*)&gsm[2 * (t0 - 256)] = fo;   // one ds_write_b64
    }
    bar_lds();
    if (t0 < 256) {
      float2 fo = *(const float2*)&gsm[2 * t0];  // one ds_read_b64
      cst = fo.x * cst + ig * gg;
      hlast = fo.y * tanhf2(cst);
      ((_Float16*)hsm)[t0] = (_Float16)hlast;
    }
    bar_lds();
  }
  if (t0 < 256) hfin[(size_t)b * HH + t0] = hlast;
}

// ---------------------------------------------------------------------------
// K3: out[b][c] = h_last[b] . W_cls[c] + b_cls[c]
// ---------------------------------------------------------------------------
__global__ __launch_bounds__(256) void cls_k(
    const float* __restrict__ hfin, const float* __restrict__ Wcls,
    const float* __restrict__ bcls, float* __restrict__ out) {
  __shared__ float part[4][NC];
  const int b = blockIdx.x, tid = threadIdx.x;
  const int lane = tid & 63, wave = tid >> 6;
  float hv = hfin[(size_t)b * HH + tid];
#pragma unroll
  for (int c = 0; c < NC; ++c) {
    float p = hv * Wcls[c * HH + tid];
#pragma unroll
    for (int off = 32; off >= 1; off >>= 1) p += __shfl_down(p, off, 64);
    if (lane == 0) part[wave][c] = p;
  }
  __syncthreads();
  if (tid < NC) {
    out[(size_t)b * NC + tid] =
        part[0][tid] + part[1][tid] + part[2][tid] + part[3][tid] + bcls[tid];
  }
}

// ---------------------------------------------------------------------------
extern "C" void kernel_launch(void* const* d_in, const int* in_sizes, int n_in,
                              void* d_out, int out_size, void* d_ws, size_t ws_size,
                              hipStream_t stream) {
  (void)in_sizes; (void)n_in; (void)out_size; (void)ws_size;
  const float* x    = (const float*)d_in[0];
  const float* key  = (const float*)d_in[1];
  const float* Wih  = (const float*)d_in[2];
  const float* Whh  = (const float*)d_in[3];
  const float* bih  = (const float*)d_in[4];
  const float* bhh  = (const float*)d_in[5];
  const float* Wcls = (const float*)d_in[6];
  const float* bcls = (const float*)d_in[7];
  float* out = (float*)d_out;

  char* ws = (char*)d_ws;
  size_t off = 0;
  uint32_t* xpk  = (uint32_t*)(ws + off); off += (size_t)BB * TT * 512 * 4;  // 268 MB
  uint32_t* wrg  = (uint32_t*)(ws + off); off += (size_t)112 * G4 * 4;
  uint32_t* wld  = (uint32_t*)(ws + off); off += (size_t)8 * 512 * 16;       // 64 KB
  _Float16* WcT  = (_Float16*)(ws + off); off += (size_t)G4 * II * 2;
  float* biasc   = (float*)(ws + off);    off += (size_t)G4 * 4;
  float* hfin    = (float*)(ws + off);    off += (size_t)BB * HH * 4;

  hipLaunchKernelGGL(prep_wc,  dim3(II),  dim3(G4),  0, stream, key, Wih, bih, bhh, WcT, biasc);
  hipLaunchKernelGGL(prep_whh, dim3(512), dim3(256), 0, stream, Whh, wrg, wld);
  hipLaunchKernelGGL(gemm_xproj, dim3(G4 / 128, (BB * TT) / 128), dim3(256), 0, stream,
                     x, WcT, biasc, (_Float16*)xpk);
  hipLaunchKernelGGL(lstm_seq, dim3(BB), dim3(512), 0, stream, xpk, wrg, (const uint4*)wld, hfin);
  hipLaunchKernelGGL(cls_k,    dim3(BB), dim3(256), 0, stream, hfin, Wcls, bcls, out);
}